// Round 14
// baseline (295.580 us; speedup 1.0000x reference)
//
#include <hip/hip_runtime.h>

#define D_IN 128
#define HID 256
#define BKT_SHIFT 6
#define BKT_SIZE 64         // nodes per bucket; pack (src<<6)|(dst&63), src<2^16
#define BKT_CAP 3072        // fixed edge capacity per bucket (mean ~2048, +22 sigma)
#define NBKT_MAX 1024       // N <= 65536 -> nbkt <= 1024 (front LDS bound)
#define CHUNK 4096          // edges per chunk in binning phase
#define PAD_SLACK 512       // per-bucket csr slack >= max pad (7*64=448)
#define LSTR 264            // LDS row stride (bf16) for h tile (528B/row)
#define ASTR 136            // LDS row stride (bf16) for A tile
#define FSTR 132            // LDS row stride (f32) accf tile; 132*4=528B == LSTR row (exact alias)

typedef __attribute__((ext_vector_type(8))) short short8;   // 8 bf16 MFMA A/B frag
typedef __attribute__((ext_vector_type(4))) float floatx4;  // MFMA C/D frag
typedef __attribute__((ext_vector_type(4))) int intx4;

// fp32 -> bf16 (RNE), branch-free; inputs finite
static __device__ __forceinline__ unsigned short f2b(float f) {
  unsigned u = __float_as_uint(f);
  unsigned r = (u + 0x7fffu + ((u >> 16) & 1u)) >> 16;
  return (unsigned short)r;
}

static __device__ __forceinline__ void unpack8(uint4 v, float* f) {
  f[0] = __uint_as_float(v.x << 16); f[1] = __uint_as_float(v.x & 0xffff0000u);
  f[2] = __uint_as_float(v.y << 16); f[3] = __uint_as_float(v.y & 0xffff0000u);
  f[4] = __uint_as_float(v.z << 16); f[5] = __uint_as_float(v.z & 0xffff0000u);
  f[6] = __uint_as_float(v.w << 16); f[7] = __uint_as_float(v.w & 0xffff0000u);
}

static __device__ __forceinline__ void acc_add(float* acc, uint4 v) {
  float g[8];
  unpack8(v, g);
#pragma unroll
  for (int d = 0; d < 8; ++d) acc[d] += g[d];
}

// PRESCALED weight-free gather over one padded row (R13-proven, used by agg2).
static __device__ __forceinline__ void gather_row(float* acc, const uint4* __restrict__ Hq,
                                                  const int* __restrict__ csr,
                                                  int2 se, int lane) {
  intx4 c0 = *(const intx4*)(csr + se.x);
  intx4 c1 = *(const intx4*)(csr + se.x + 4);
  for (int j = se.x; j < se.y; ) {
    const int jn = j + 8;
    const int jp = (jn < se.y) ? jn : se.x;  // clamp: last-iter prefetch unused
    intx4 n0 = *(const intx4*)(csr + jp);
    intx4 n1 = *(const intx4*)(csr + jp + 4);
    uint4 v0 = Hq[(size_t)c0.x * 16 + lane];
    uint4 v1 = Hq[(size_t)c0.y * 16 + lane];
    uint4 v2 = Hq[(size_t)c0.z * 16 + lane];
    uint4 v3 = Hq[(size_t)c0.w * 16 + lane];
    uint4 v4 = Hq[(size_t)c1.x * 16 + lane];
    uint4 v5 = Hq[(size_t)c1.y * 16 + lane];
    uint4 v6 = Hq[(size_t)c1.z * 16 + lane];
    uint4 v7 = Hq[(size_t)c1.w * 16 + lane];
    acc_add(acc, v0);
    acc_add(acc, v1);
    acc_add(acc, v2);
    acc_add(acc, v3);
    acc_add(acc, v4);
    acc_add(acc, v5);
    acc_add(acc, v6);
    acc_add(acc, v7);
    c0 = n0; c1 = n1; j = jn;
  }
}

// ========== K1 (fused): bin_scatter + W transposes + sentinels ==========

__global__ __launch_bounds__(256) void fused_front_kernel(
    const int* __restrict__ src, const int* __restrict__ dst,
    int* __restrict__ bkt_cursor, int* __restrict__ ebuf, int E, int nbkt, int nchunk,
    const float* __restrict__ W1, unsigned short* __restrict__ Wt1,
    const float* __restrict__ W2, unsigned short* __restrict__ Wt2,
    float* __restrict__ dinv, unsigned short* __restrict__ xb,
    unsigned short* __restrict__ tb, int N) {
  const int bid = blockIdx.x;
  const int tid = threadIdx.x;
  if (bid < nchunk) {
    __shared__ int hist[NBKT_MAX];
    __shared__ int bbase[NBKT_MAX];
    for (int b = tid; b < nbkt; b += 256) hist[b] = 0;
    __syncthreads();
    const int base = bid * CHUNK;
    const int end = min(base + CHUNK, E);
    for (int e = base + tid; e < end; e += 256)
      atomicAdd(&hist[dst[e] >> BKT_SHIFT], 1);
    __syncthreads();
    for (int b = tid; b < nbkt; b += 256) {
      int c = hist[b];
      bbase[b] = c > 0 ? atomicAdd(&bkt_cursor[b], c) : 0;  // relative base
      hist[b] = 0;  // reuse as intra-block cursor
    }
    __syncthreads();
    for (int e = base + tid; e < end; e += 256) {
      int d = dst[e];
      int b = d >> BKT_SHIFT;
      int off = atomicAdd(&hist[b], 1);
      int rel = bbase[b] + off;
      if (rel < BKT_CAP)  // capacity guard (never trips for uniform input)
        ebuf[b * BKT_CAP + rel] = (src[e] << BKT_SHIFT) | (d & (BKT_SIZE - 1));
    }
    return;
  }
  if (bid < nchunk + 128) {
    // W1[K=128][N=256] -> Wt1[N][K]
    int e = (bid - nchunk) * 256 + tid;
    int k = e >> 8, n = e & 255;
    Wt1[(size_t)n * D_IN + k] = f2b(W1[e]);
  } else if (bid < nchunk + 256) {
    // W2[K=256][N=128] -> Wt2[N][K]
    int e = (bid - nchunk - 128) * 256 + tid;
    int k = e >> 7, n = e & 127;
    Wt2[(size_t)n * HID + k] = f2b(W2[e]);
  } else {
    // sentinels: dinv[N]=0; zero row N of xb/tb (pad slots gather zero rows)
    if (tid == 0) dinv[N] = 0.f;
    if (tid < 64)       ((unsigned*)(xb + (size_t)N * D_IN))[tid]      = 0u;
    else if (tid < 128) ((unsigned*)(tb + (size_t)N * D_IN))[tid - 64] = 0u;
  }
}

// ========== K2: per-bucket degree hist -> dinv + rowse; padded CSR; x prescale ==========

__global__ __launch_bounds__(256) void bucket_build_kernel(const int* __restrict__ ebuf,
                                                           const int* __restrict__ bkt_cursor,
                                                           const float4* __restrict__ x4,
                                                           unsigned short* __restrict__ xb,
                                                           float* __restrict__ dinv,
                                                           int2* __restrict__ rowse,
                                                           int* __restrict__ csr,
                                                           int N, int nbkt) {
  __shared__ int hist[BKT_SIZE];
  __shared__ int srs[BKT_SIZE];
  __shared__ float sdinv[BKT_SIZE];
  const int b = blockIdx.x;
  const int tid = threadIdx.x;
  const int node0 = b << BKT_SHIFT;
  const int nloc = min(BKT_SIZE, N - node0);
  const int ebeg = b * BKT_CAP;
  const int eend = ebeg + min(bkt_cursor[b], BKT_CAP);

  if (tid < BKT_SIZE) hist[tid] = 0;
  __syncthreads();
  for (int e = ebeg + tid; e < eend; e += 256)
    atomicAdd(&hist[ebuf[e] & (BKT_SIZE - 1)], 1);
  __syncthreads();

  // padded (multiple-of-8) 64-wide exclusive scan: wave 0 only (tid==lane)
  if (tid < BKT_SIZE) {
    const int h = hist[tid];
    const int p = (h + 7) & ~7;
    int incl = p;
#pragma unroll
    for (int off = 1; off < 64; off <<= 1) {
      int t = __shfl_up(incl, off);
      if (tid >= off) incl += t;
    }
    const int ex = incl - p;
    float dv = rsqrtf((float)(h + 1));
    sdinv[tid] = dv;
    if (tid < nloc) {
      int st = b * (BKT_CAP + PAD_SLACK) + ex;
      dinv[node0 + tid] = dv;
      rowse[node0 + tid] = make_int2(st, st + p);
      srs[tid] = st;
    }
  }
  __syncthreads();
  if (tid < BKT_SIZE) hist[tid] = 0;  // reuse as per-node cursors
  __syncthreads();

  for (int e = ebeg + tid; e < eend; e += 256) {
    int u = ebuf[e];
    int l = u & (BKT_SIZE - 1);
    int pos = atomicAdd(&hist[l], 1);
    csr[srs[l] + pos] = u >> BKT_SHIFT;
  }
  __syncthreads();
  for (int l = tid; l < nloc; l += 256) {
    int deg = hist[l];
    int pp = (deg + 7) & ~7;
    int s0 = srs[l];
    for (int q = s0 + deg; q < s0 + pp; ++q) csr[q] = N;  // sentinel: zero row
  }

  // x (fp32) -> xb_s (bf16, prescaled by dinv): 64 rows x 32 float4
  for (int i = tid; i < nloc * 32; i += 256) {
    const int l = i >> 5;
    const float dv = sdinv[l];
    float4 v = x4[(size_t)(node0 + l) * 32 + (i & 31)];
    ushort4 o;
    o.x = f2b(v.x * dv); o.y = f2b(v.y * dv);
    o.z = f2b(v.z * dv); o.w = f2b(v.w * dv);
    *(ushort4*)(xb + (size_t)(node0 + l) * D_IN + (i & 31) * 4) = o;
  }
}

// ========== K3: EDGE-BALANCED agg1 -> LDS f32 tile -> gemm12 -> tb_s ==========
// The block's 32 rows are csr-contiguous (same bucket half, ascending, 8-padded).
// Gather is partitioned by EDGE-CHUNKS (8 edges, never straddles a row) equally
// across the 32 lane-groups — removes the max-degree convoy at the old barrier
// (E[max of 32 rows] ~ 1.4x mean -> ~1.0x). Partials accumulate in registers per
// row-run and flush via LDS f32 atomicAdd (ds_add_f32) into accf, which EXACTLY
// aliases the hs region (528B/row both) so LDS stays 25.7KB (occupancy unchanged).
// Convert step adds the self term, applies dv, emits bf16 as_. gemm unchanged.

__global__ __launch_bounds__(512, 4) void agg1_gemm_kernel(
    const uint4* __restrict__ Hq, const int2* __restrict__ rowse,
    const int* __restrict__ csr, const float* __restrict__ dinv,
    const unsigned short* __restrict__ Wt1, const float* __restrict__ b1,
    const unsigned short* __restrict__ Wt2, unsigned short* __restrict__ T, int M) {
  __shared__ union {
    float accf[32][FSTR];                 // 16896 B (gather phase)
    unsigned short hs[32][LSTR];          // 16896 B (gemm phase) — exact alias
  } smu;
  __shared__ unsigned short as_[32][ASTR];  // Â x tile (bf16)
  __shared__ int srow[33];                  // row starts + end sentinel
  const int tid = threadIdx.x;
  const int node0 = blockIdx.x * 32;
  const int nloc = min(32, M - node0);      // grid = ceil(M/32) -> nloc >= 1

  // ---- edge-balanced gather phase ----
  {
    const int glane = tid & 15;
    const int grp = tid >> 4;  // 0..31
    if (tid < nloc) {
      int2 se = rowse[node0 + tid];
      srow[tid] = se.x;
      if (tid == nloc - 1) srow[nloc] = se.y;
    }
    for (int i = tid; i < 32 * FSTR; i += 512) (&smu.accf[0][0])[i] = 0.f;
    __syncthreads();

    const int s0 = srow[0];
    const int C = (srow[nloc] - s0) >> 3;           // 8-edge chunks in block range
    const int c0 = (C * grp) >> 5, c1 = (C * (grp + 1)) >> 5;
    if (c0 < c1) {
      int r = 0;
      int off = s0 + c0 * 8;
      while (srow[r + 1] <= off) ++r;               // rows are 8-aligned: no straddle
      float acc[8] = {0.f, 0.f, 0.f, 0.f, 0.f, 0.f, 0.f, 0.f};
      for (int c = c0; c < c1; ++c) {
        off = s0 + c * 8;
        if (off >= srow[r + 1]) {                   // row transition: flush partials
#pragma unroll
          for (int d = 0; d < 8; ++d) atomicAdd(&smu.accf[r][glane * 8 + d], acc[d]);
#pragma unroll
          for (int d = 0; d < 8; ++d) acc[d] = 0.f;
          while (srow[r + 1] <= off) ++r;
        }
        intx4 i0 = *(const intx4*)(csr + off);
        intx4 i1 = *(const intx4*)(csr + off + 4);
        uint4 v0 = Hq[(size_t)i0.x * 16 + glane];
        uint4 v1 = Hq[(size_t)i0.y * 16 + glane];
        uint4 v2 = Hq[(size_t)i0.z * 16 + glane];
        uint4 v3 = Hq[(size_t)i0.w * 16 + glane];
        uint4 v4 = Hq[(size_t)i1.x * 16 + glane];
        uint4 v5 = Hq[(size_t)i1.y * 16 + glane];
        uint4 v6 = Hq[(size_t)i1.z * 16 + glane];
        uint4 v7 = Hq[(size_t)i1.w * 16 + glane];
        acc_add(acc, v0);
        acc_add(acc, v1);
        acc_add(acc, v2);
        acc_add(acc, v3);
        acc_add(acc, v4);
        acc_add(acc, v5);
        acc_add(acc, v6);
        acc_add(acc, v7);
      }
#pragma unroll
      for (int d = 0; d < 8; ++d) atomicAdd(&smu.accf[r][glane * 8 + d], acc[d]);
    }
    __syncthreads();

    // convert: as_[l] = f2b(dv * (accf[l] + self)); rows >= nloc -> 0 (dv=0)
    {
      const int l = tid >> 4, cg = tid & 15;
      float self[8] = {0.f, 0.f, 0.f, 0.f, 0.f, 0.f, 0.f, 0.f};
      float dv = 0.f;
      if (l < nloc) {
        dv = dinv[node0 + l];
        uint4 sv = Hq[(size_t)(node0 + l) * 16 + cg];
        unpack8(sv, self);
      }
      uint4 o;
      float a0 = (smu.accf[l][cg * 8 + 0] + self[0]) * dv;
      float a1 = (smu.accf[l][cg * 8 + 1] + self[1]) * dv;
      float a2 = (smu.accf[l][cg * 8 + 2] + self[2]) * dv;
      float a3 = (smu.accf[l][cg * 8 + 3] + self[3]) * dv;
      float a4 = (smu.accf[l][cg * 8 + 4] + self[4]) * dv;
      float a5 = (smu.accf[l][cg * 8 + 5] + self[5]) * dv;
      float a6 = (smu.accf[l][cg * 8 + 6] + self[6]) * dv;
      float a7 = (smu.accf[l][cg * 8 + 7] + self[7]) * dv;
      o.x = (unsigned)f2b(a0) | ((unsigned)f2b(a1) << 16);
      o.y = (unsigned)f2b(a2) | ((unsigned)f2b(a3) << 16);
      o.z = (unsigned)f2b(a4) | ((unsigned)f2b(a5) << 16);
      o.w = (unsigned)f2b(a6) | ((unsigned)f2b(a7) << 16);
      *(uint4*)&as_[l][cg * 8] = o;
    }
  }
  __syncthreads();  // accf dead from here; smu.hs may be written

  // ---- gemm phase (8-wave column split, R9-exact) ----
  const int wave = tid >> 6;  // 0..7
  const int lane = tid & 63;
  const int quad = lane >> 4;
  const int l16 = lane & 15;

  // phase 1: hs[0..31][wave*32 .. +32) = relu(as_ @ W1 + b1)
  const short8* bp1 = (const short8*)(Wt1 + (size_t)(wave * 32 + l16) * D_IN + quad * 8);
  floatx4 acc1[2][2];  // [row-group][col-tile]
#pragma unroll
  for (int g = 0; g < 2; ++g)
#pragma unroll
    for (int t = 0; t < 2; ++t) acc1[g][t] = floatx4{0.f, 0.f, 0.f, 0.f};

#pragma unroll
  for (int kt = 0; kt < 4; ++kt) {  // K = 128
    short8 a0 = *(const short8*)&as_[0 * 16 + l16][kt * 32 + quad * 8];
    short8 a1 = *(const short8*)&as_[1 * 16 + l16][kt * 32 + quad * 8];
#pragma unroll
    for (int t = 0; t < 2; ++t) {
      short8 b = bp1[kt * 4 + t * 256];  // t*16 rows * 16 short8/row
      acc1[0][t] = __builtin_amdgcn_mfma_f32_16x16x32_bf16(a0, b, acc1[0][t], 0, 0, 0);
      acc1[1][t] = __builtin_amdgcn_mfma_f32_16x16x32_bf16(a1, b, acc1[1][t], 0, 0, 0);
    }
  }
#pragma unroll
  for (int t = 0; t < 2; ++t) {
    const float bv = b1[wave * 32 + t * 16 + l16];
#pragma unroll
    for (int g = 0; g < 2; ++g)
#pragma unroll
      for (int r = 0; r < 4; ++r) {
        float v = acc1[g][t][r] + bv;
        v = v > 0.f ? v : 0.f;
        smu.hs[g * 16 + quad * 4 + r][wave * 32 + t * 16 + l16] = f2b(v);
      }
  }
  __syncthreads();

  // phase 2: t[0..31][wave*16 .. +16) = hs @ Wt2^T
  const short8* bp2 = (const short8*)(Wt2 + (size_t)(wave * 16 + l16) * HID + quad * 8);
  floatx4 acc2[2];
#pragma unroll
  for (int g = 0; g < 2; ++g) acc2[g] = floatx4{0.f, 0.f, 0.f, 0.f};

#pragma unroll
  for (int kt = 0; kt < 8; ++kt) {  // K = 256
    short8 a0 = *(const short8*)&smu.hs[0 * 16 + l16][kt * 32 + quad * 8];
    short8 a1 = *(const short8*)&smu.hs[1 * 16 + l16][kt * 32 + quad * 8];
    short8 b = bp2[kt * 4];
    acc2[0] = __builtin_amdgcn_mfma_f32_16x16x32_bf16(a0, b, acc2[0], 0, 0, 0);
    acc2[1] = __builtin_amdgcn_mfma_f32_16x16x32_bf16(a1, b, acc2[1], 0, 0, 0);
  }
  __syncthreads();  // all waves done reading hs before overwrite

  // t-tile -> LDS, PRESCALED: tb_s[row] = dinv[row] * t[row]
#pragma unroll
  for (int g = 0; g < 2; ++g)
#pragma unroll
    for (int r = 0; r < 4; ++r) {
      int rr = node0 + g * 16 + quad * 4 + r;
      float dvr = dinv[rr < M ? rr : M];  // dinv[M..N] valid; tail rows unstored
      smu.hs[g * 16 + quad * 4 + r][wave * 16 + l16] = f2b(acc2[g][r] * dvr);
    }
  __syncthreads();

  // coalesced store: 32 rows x 128 cols bf16; 512 threads x 16B
  {
    const int r = tid >> 4;
    const int c = (tid & 15) * 8;
    const int row = node0 + r;
    uint4 v = *(const uint4*)&smu.hs[r][c];
    if (row < M) *(uint4*)&T[(size_t)row * D_IN + c] = v;
  }
}

// ========== K4: agg2 (Â tb_s + skip + bias): weight-free gather, final *dv ==========

__global__ __launch_bounds__(256) void agg2_kernel(const uint4* __restrict__ Hq,
                                                   const int2* __restrict__ rowse,
                                                   const int* __restrict__ csr,
                                                   const float* __restrict__ dinv,
                                                   const float* __restrict__ skip,
                                                   const float* __restrict__ bias,
                                                   float* __restrict__ OUT, int n) {
  const int lane = threadIdx.x & 15;
  const int node = blockIdx.x * 16 + (threadIdx.x >> 4);
  if (node >= n) return;

  const float dv = dinv[node];
  float acc[8];
  {
    uint4 sv = Hq[(size_t)node * 16 + lane];  // self term: tb_s[node]
    unpack8(sv, acc);
  }
  gather_row(acc, Hq, csr, rowse[node], lane);

  const float* sp = skip + (size_t)node * 128 + lane * 8;
  const float* bp = bias + lane * 8;
  float4 s0 = *(const float4*)sp, s1 = *(const float4*)(sp + 4);
  float4 b0 = *(const float4*)bp, b1 = *(const float4*)(bp + 4);
  float* op = OUT + (size_t)node * 128 + lane * 8;
  *(float4*)op = make_float4(fmaf(acc[0], dv, s0.x + b0.x), fmaf(acc[1], dv, s0.y + b0.y),
                             fmaf(acc[2], dv, s0.z + b0.z), fmaf(acc[3], dv, s0.w + b0.w));
  *(float4*)(op + 4) = make_float4(fmaf(acc[4], dv, s1.x + b1.x), fmaf(acc[5], dv, s1.y + b1.y),
                                   fmaf(acc[6], dv, s1.z + b1.z), fmaf(acc[7], dv, s1.w + b1.w));
}

// ================= launch =================

extern "C" void kernel_launch(void* const* d_in, const int* in_sizes, int n_in,
                              void* d_out, int out_size, void* d_ws, size_t ws_size,
                              hipStream_t stream) {
  const float* x  = (const float*)d_in[0];
  const int*   ei = (const int*)d_in[1];
  const float* W1 = (const float*)d_in[2];
  const float* b1 = (const float*)d_in[3];
  const float* W2 = (const float*)d_in[4];
  const float* b2 = (const float*)d_in[5];
  float* out = (float*)d_out;

  const int N = in_sizes[0] / D_IN;      // requires N <= 65536 (packed ebuf)
  const int E = in_sizes[1] / 2;
  const int* srcA = ei;
  const int* dstA = ei + E;
  const int NBKT = (N + BKT_SIZE - 1) >> BKT_SHIFT;  // 782 for N=50000
  const int NCHUNK = (E + CHUNK - 1) / CHUNK;        // 391

  // ---- workspace (256B aligned) ----
  char* ws = (char*)d_ws;
  size_t off = 0;
  auto alloc = [&](size_t bytes) { void* p = ws + off; off = (off + bytes + 255) & ~(size_t)255; return p; };
  int*            bkt_cursor = (int*)           alloc((size_t)NBKT * 4);
  float*          dinv       = (float*)         alloc((size_t)(N + 1) * 4);  // +sentinel
  int2*           rowse      = (int2*)          alloc((size_t)N * 8);
  int*            ebuf       = (int*)           alloc((size_t)NBKT * BKT_CAP * 4);
  int*            csr        = (int*)           alloc((size_t)NBKT * (BKT_CAP + PAD_SLACK) * 4);
  unsigned short* xb         = (unsigned short*)alloc((size_t)(N + 1) * D_IN * 2);
  unsigned short* tb         = (unsigned short*)alloc((size_t)(N + 1) * D_IN * 2);
  unsigned short* Wt1        = (unsigned short*)alloc((size_t)D_IN * HID * 2);
  unsigned short* Wt2        = (unsigned short*)alloc((size_t)D_IN * HID * 2);

  // 1) zero relative bucket cursors
  (void)hipMemsetAsync(bkt_cursor, 0, (size_t)NBKT * 4, stream);
  // 2) K1: bin_scatter + W transposes + sentinels
  fused_front_kernel<<<NCHUNK + 256 + 1, 256, 0, stream>>>(
      srcA, dstA, bkt_cursor, ebuf, E, NBKT, NCHUNK,
      W1, Wt1, W2, Wt2, dinv, xb, tb, N);
  // 3) K2: per-bucket build + prescaled x->xb conversion (782 blocks)
  bucket_build_kernel<<<NBKT, 256, 0, stream>>>(ebuf, bkt_cursor, (const float4*)x,
                                                xb, dinv, rowse, csr, N, NBKT);
  // 4) K3: tb_s = dinv * (relu((Â x) @ W1 + b1) @ W2)   (edge-balanced gather)
  agg1_gemm_kernel<<<(N + 31) / 32, 512, 0, stream>>>((const uint4*)xb, rowse, csr, dinv,
                                                      Wt1, b1, Wt2, tb, N);
  // 5) K4: out = Â tb + x + b2   (gather of prescaled tb_s, final *dv)
  agg2_kernel<<<(N + 15) / 16, 256, 0, stream>>>((const uint4*)tb, rowse, csr,
                                                 dinv, x, b2, out, N);
}

// Round 15
// 260.655 us; speedup vs baseline: 1.1340x; 1.1340x over previous
//
#include <hip/hip_runtime.h>

#define D_IN 128
#define HID 256
#define BKT_SHIFT 6
#define BKT_SIZE 64         // nodes per bucket; pack (src<<6)|(dst&63), src<2^16
#define BKT_CAP 3072        // fixed edge capacity per bucket (mean ~2048, +22 sigma)
#define NBKT_MAX 1024       // N <= 65536 -> nbkt <= 1024 (front LDS bound)
#define CHUNK 4096          // edges per chunk in binning phase
#define PAD_SLACK 512       // per-bucket csr slack >= max pad (7*64=448)
#define LSTR 264            // LDS row stride (bf16) for h tile
#define ASTR 136            // LDS row stride (bf16) for A tile

typedef __attribute__((ext_vector_type(8))) short short8;   // 8 bf16 MFMA A/B frag
typedef __attribute__((ext_vector_type(4))) float floatx4;  // MFMA C/D frag
typedef __attribute__((ext_vector_type(4))) int intx4;

// fp32 -> bf16 (RNE), branch-free; inputs finite
static __device__ __forceinline__ unsigned short f2b(float f) {
  unsigned u = __float_as_uint(f);
  unsigned r = (u + 0x7fffu + ((u >> 16) & 1u)) >> 16;
  return (unsigned short)r;
}

static __device__ __forceinline__ void unpack8(uint4 v, float* f) {
  f[0] = __uint_as_float(v.x << 16); f[1] = __uint_as_float(v.x & 0xffff0000u);
  f[2] = __uint_as_float(v.y << 16); f[3] = __uint_as_float(v.y & 0xffff0000u);
  f[4] = __uint_as_float(v.z << 16); f[5] = __uint_as_float(v.z & 0xffff0000u);
  f[6] = __uint_as_float(v.w << 16); f[7] = __uint_as_float(v.w & 0xffff0000u);
}

static __device__ __forceinline__ void acc_add(float* acc, uint4 v) {
  float g[8];
  unpack8(v, g);
#pragma unroll
  for (int d = 0; d < 8; ++d) acc[d] += g[d];
}

// PRESCALED gather: acc += sum over row [se.x,se.y) of H_s[src] (H_s already
// carries dinv[src]; caller applies its own dv at the end). Per 8 edges: 2 csr
// loads + 8 uint4 gathers (no random dinv loads). One-iteration csr prefetch.
static __device__ __forceinline__ void gather_row(float* acc, const uint4* __restrict__ Hq,
                                                  const int* __restrict__ csr,
                                                  int2 se, int lane) {
  intx4 c0 = *(const intx4*)(csr + se.x);
  intx4 c1 = *(const intx4*)(csr + se.x + 4);
  for (int j = se.x; j < se.y; ) {
    const int jn = j + 8;
    const int jp = (jn < se.y) ? jn : se.x;  // clamp: last-iter prefetch unused
    intx4 n0 = *(const intx4*)(csr + jp);
    intx4 n1 = *(const intx4*)(csr + jp + 4);
    uint4 v0 = Hq[(size_t)c0.x * 16 + lane];
    uint4 v1 = Hq[(size_t)c0.y * 16 + lane];
    uint4 v2 = Hq[(size_t)c0.z * 16 + lane];
    uint4 v3 = Hq[(size_t)c0.w * 16 + lane];
    uint4 v4 = Hq[(size_t)c1.x * 16 + lane];
    uint4 v5 = Hq[(size_t)c1.y * 16 + lane];
    uint4 v6 = Hq[(size_t)c1.z * 16 + lane];
    uint4 v7 = Hq[(size_t)c1.w * 16 + lane];
    acc_add(acc, v0);
    acc_add(acc, v1);
    acc_add(acc, v2);
    acc_add(acc, v3);
    acc_add(acc, v4);
    acc_add(acc, v5);
    acc_add(acc, v6);
    acc_add(acc, v7);
    c0 = n0; c1 = n1; j = jn;
  }
}

// ========== K1 (fused): bin_scatter + W transposes + sentinels ==========
// x->xb conversion lives in bucket_build (needs dinv for prescale).

__global__ __launch_bounds__(256) void fused_front_kernel(
    const int* __restrict__ src, const int* __restrict__ dst,
    int* __restrict__ bkt_cursor, int* __restrict__ ebuf, int E, int nbkt, int nchunk,
    const float* __restrict__ W1, unsigned short* __restrict__ Wt1,
    const float* __restrict__ W2, unsigned short* __restrict__ Wt2,
    float* __restrict__ dinv, unsigned short* __restrict__ xb,
    unsigned short* __restrict__ tb, int N) {
  const int bid = blockIdx.x;
  const int tid = threadIdx.x;
  if (bid < nchunk) {
    __shared__ int hist[NBKT_MAX];
    __shared__ int bbase[NBKT_MAX];
    for (int b = tid; b < nbkt; b += 256) hist[b] = 0;
    __syncthreads();
    const int base = bid * CHUNK;
    const int end = min(base + CHUNK, E);
    for (int e = base + tid; e < end; e += 256)
      atomicAdd(&hist[dst[e] >> BKT_SHIFT], 1);
    __syncthreads();
    for (int b = tid; b < nbkt; b += 256) {
      int c = hist[b];
      bbase[b] = c > 0 ? atomicAdd(&bkt_cursor[b], c) : 0;  // relative base
      hist[b] = 0;  // reuse as intra-block cursor
    }
    __syncthreads();
    for (int e = base + tid; e < end; e += 256) {
      int d = dst[e];
      int b = d >> BKT_SHIFT;
      int off = atomicAdd(&hist[b], 1);
      int rel = bbase[b] + off;
      if (rel < BKT_CAP)  // capacity guard (never trips for uniform input)
        ebuf[b * BKT_CAP + rel] = (src[e] << BKT_SHIFT) | (d & (BKT_SIZE - 1));
    }
    return;
  }
  if (bid < nchunk + 128) {
    // W1[K=128][N=256] -> Wt1[N][K]
    int e = (bid - nchunk) * 256 + tid;
    int k = e >> 8, n = e & 255;
    Wt1[(size_t)n * D_IN + k] = f2b(W1[e]);
  } else if (bid < nchunk + 256) {
    // W2[K=256][N=128] -> Wt2[N][K]
    int e = (bid - nchunk - 128) * 256 + tid;
    int k = e >> 7, n = e & 127;
    Wt2[(size_t)n * HID + k] = f2b(W2[e]);
  } else {
    // sentinels: dinv[N]=0; zero row N of xb/tb (pad slots gather zero rows)
    if (tid == 0) dinv[N] = 0.f;
    if (tid < 64)       ((unsigned*)(xb + (size_t)N * D_IN))[tid]      = 0u;
    else if (tid < 128) ((unsigned*)(tb + (size_t)N * D_IN))[tid - 64] = 0u;
  }
}

// ========== K2: per-bucket degree hist -> dinv + rowse; padded CSR; x prescale ==========
// 64 nodes/bucket, 782 blocks. Converts its 64 x rows to PRESCALED bf16
// (xb_s[n] = dinv[n]*x[n]) — placed where dinv lives.

__global__ __launch_bounds__(256) void bucket_build_kernel(const int* __restrict__ ebuf,
                                                           const int* __restrict__ bkt_cursor,
                                                           const float4* __restrict__ x4,
                                                           unsigned short* __restrict__ xb,
                                                           float* __restrict__ dinv,
                                                           int2* __restrict__ rowse,
                                                           int* __restrict__ csr,
                                                           int N, int nbkt) {
  __shared__ int hist[BKT_SIZE];
  __shared__ int srs[BKT_SIZE];
  __shared__ float sdinv[BKT_SIZE];
  const int b = blockIdx.x;
  const int tid = threadIdx.x;
  const int node0 = b << BKT_SHIFT;
  const int nloc = min(BKT_SIZE, N - node0);
  const int ebeg = b * BKT_CAP;
  const int eend = ebeg + min(bkt_cursor[b], BKT_CAP);

  if (tid < BKT_SIZE) hist[tid] = 0;
  __syncthreads();
  for (int e = ebeg + tid; e < eend; e += 256)
    atomicAdd(&hist[ebuf[e] & (BKT_SIZE - 1)], 1);
  __syncthreads();

  // padded (multiple-of-8) 64-wide exclusive scan: wave 0 only (tid==lane)
  if (tid < BKT_SIZE) {
    const int h = hist[tid];
    const int p = (h + 7) & ~7;
    int incl = p;
#pragma unroll
    for (int off = 1; off < 64; off <<= 1) {
      int t = __shfl_up(incl, off);
      if (tid >= off) incl += t;
    }
    const int ex = incl - p;
    float dv = rsqrtf((float)(h + 1));
    sdinv[tid] = dv;
    if (tid < nloc) {
      int st = b * (BKT_CAP + PAD_SLACK) + ex;
      dinv[node0 + tid] = dv;
      rowse[node0 + tid] = make_int2(st, st + p);
      srs[tid] = st;
    }
  }
  __syncthreads();
  if (tid < BKT_SIZE) hist[tid] = 0;  // reuse as per-node cursors
  __syncthreads();

  for (int e = ebeg + tid; e < eend; e += 256) {
    int u = ebuf[e];
    int l = u & (BKT_SIZE - 1);
    int pos = atomicAdd(&hist[l], 1);
    csr[srs[l] + pos] = u >> BKT_SHIFT;
  }
  __syncthreads();
  for (int l = tid; l < nloc; l += 256) {
    int deg = hist[l];
    int pp = (deg + 7) & ~7;
    int s0 = srs[l];
    for (int q = s0 + deg; q < s0 + pp; ++q) csr[q] = N;  // sentinel: zero row
  }

  // x (fp32) -> xb_s (bf16, prescaled by dinv): 64 rows x 32 float4
  for (int i = tid; i < nloc * 32; i += 256) {
    const int l = i >> 5;
    const float dv = sdinv[l];
    float4 v = x4[(size_t)(node0 + l) * 32 + (i & 31)];
    ushort4 o;
    o.x = f2b(v.x * dv); o.y = f2b(v.y * dv);
    o.z = f2b(v.z * dv); o.w = f2b(v.w * dv);
    *(ushort4*)(xb + (size_t)(node0 + l) * D_IN + (i & 31) * 4) = o;
  }
}

// ========== K3: agg1 (Â x, prescaled) -> LDS A-tile -> gemm12 -> tb_s ==========
// Gather is weight-free (xb prescaled); A-tile value = dv * (self + sum).
// Epilogue stores tb_s[row] = dinv[row] * t[row] so agg2's gather is also free.
// R13-exact (node-partitioned gather; edge-balancing regressed — R14: LDS-atomic
// flush cost 6.1M bank conflicts; convoy already absorbed by cross-block overlap).

__global__ __launch_bounds__(512, 4) void agg1_gemm_kernel(
    const uint4* __restrict__ Hq, const int2* __restrict__ rowse,
    const int* __restrict__ csr, const float* __restrict__ dinv,
    const unsigned short* __restrict__ Wt1, const float* __restrict__ b1,
    const unsigned short* __restrict__ Wt2, unsigned short* __restrict__ T, int M) {
  __shared__ unsigned short as_[32][ASTR];  // Â x tile (bf16)
  __shared__ unsigned short hs[32][LSTR];   // h tile (bf16)
  const int tid = threadIdx.x;
  const int node0 = blockIdx.x * 32;

  // ---- agg phase: 32 nodes x 16 lanes ----
  {
    const int glane = tid & 15;
    const int lrow = tid >> 4;  // 0..31
    const int node = node0 + lrow;
    float acc[8] = {0.f, 0.f, 0.f, 0.f, 0.f, 0.f, 0.f, 0.f};
    float dv = 0.f;
    if (node < M) {
      dv = dinv[node];
      uint4 sv = Hq[(size_t)node * 16 + glane];  // self term: x_s[node]
      unpack8(sv, acc);
      gather_row(acc, Hq, csr, rowse[node], glane);
    }
    uint4 o;
    o.x = (unsigned)f2b(acc[0] * dv) | ((unsigned)f2b(acc[1] * dv) << 16);
    o.y = (unsigned)f2b(acc[2] * dv) | ((unsigned)f2b(acc[3] * dv) << 16);
    o.z = (unsigned)f2b(acc[4] * dv) | ((unsigned)f2b(acc[5] * dv) << 16);
    o.w = (unsigned)f2b(acc[6] * dv) | ((unsigned)f2b(acc[7] * dv) << 16);
    *(uint4*)&as_[lrow][glane * 8] = o;  // feature c at as_[row][c]
  }
  __syncthreads();

  // ---- gemm phase (8-wave column split) ----
  const int wave = tid >> 6;  // 0..7
  const int lane = tid & 63;
  const int quad = lane >> 4;
  const int l16 = lane & 15;

  // phase 1: hs[0..31][wave*32 .. +32) = relu(as_ @ W1 + b1)
  const short8* bp1 = (const short8*)(Wt1 + (size_t)(wave * 32 + l16) * D_IN + quad * 8);
  floatx4 acc1[2][2];  // [row-group][col-tile]
#pragma unroll
  for (int g = 0; g < 2; ++g)
#pragma unroll
    for (int t = 0; t < 2; ++t) acc1[g][t] = floatx4{0.f, 0.f, 0.f, 0.f};

#pragma unroll
  for (int kt = 0; kt < 4; ++kt) {  // K = 128
    short8 a0 = *(const short8*)&as_[0 * 16 + l16][kt * 32 + quad * 8];
    short8 a1 = *(const short8*)&as_[1 * 16 + l16][kt * 32 + quad * 8];
#pragma unroll
    for (int t = 0; t < 2; ++t) {
      short8 b = bp1[kt * 4 + t * 256];  // t*16 rows * 16 short8/row
      acc1[0][t] = __builtin_amdgcn_mfma_f32_16x16x32_bf16(a0, b, acc1[0][t], 0, 0, 0);
      acc1[1][t] = __builtin_amdgcn_mfma_f32_16x16x32_bf16(a1, b, acc1[1][t], 0, 0, 0);
    }
  }
#pragma unroll
  for (int t = 0; t < 2; ++t) {
    const float bv = b1[wave * 32 + t * 16 + l16];
#pragma unroll
    for (int g = 0; g < 2; ++g)
#pragma unroll
      for (int r = 0; r < 4; ++r) {
        float v = acc1[g][t][r] + bv;
        v = v > 0.f ? v : 0.f;
        hs[g * 16 + quad * 4 + r][wave * 32 + t * 16 + l16] = f2b(v);
      }
  }
  __syncthreads();

  // phase 2: t[0..31][wave*16 .. +16) = hs @ Wt2^T
  const short8* bp2 = (const short8*)(Wt2 + (size_t)(wave * 16 + l16) * HID + quad * 8);
  floatx4 acc2[2];
#pragma unroll
  for (int g = 0; g < 2; ++g) acc2[g] = floatx4{0.f, 0.f, 0.f, 0.f};

#pragma unroll
  for (int kt = 0; kt < 8; ++kt) {  // K = 256
    short8 a0 = *(const short8*)&hs[0 * 16 + l16][kt * 32 + quad * 8];
    short8 a1 = *(const short8*)&hs[1 * 16 + l16][kt * 32 + quad * 8];
    short8 b = bp2[kt * 4];
    acc2[0] = __builtin_amdgcn_mfma_f32_16x16x32_bf16(a0, b, acc2[0], 0, 0, 0);
    acc2[1] = __builtin_amdgcn_mfma_f32_16x16x32_bf16(a1, b, acc2[1], 0, 0, 0);
  }
  __syncthreads();  // all waves done reading hs before overwrite

  // t-tile -> LDS, PRESCALED: tb_s[row] = dinv[row] * t[row]
#pragma unroll
  for (int g = 0; g < 2; ++g)
#pragma unroll
    for (int r = 0; r < 4; ++r) {
      int rr = node0 + g * 16 + quad * 4 + r;
      float dvr = dinv[rr < M ? rr : M];  // dinv[M..N] valid; tail rows unstored
      hs[g * 16 + quad * 4 + r][wave * 16 + l16] = f2b(acc2[g][r] * dvr);
    }
  __syncthreads();

  // coalesced store: 32 rows x 128 cols bf16; 512 threads x 16B
  {
    const int r = tid >> 4;
    const int c = (tid & 15) * 8;
    const int row = node0 + r;
    uint4 v = *(const uint4*)&hs[r][c];
    if (row < M) *(uint4*)&T[(size_t)row * D_IN + c] = v;
  }
}

// ========== K4: agg2 (Â tb_s + skip + bias): weight-free gather, final *dv ==========

__global__ __launch_bounds__(256) void agg2_kernel(const uint4* __restrict__ Hq,
                                                   const int2* __restrict__ rowse,
                                                   const int* __restrict__ csr,
                                                   const float* __restrict__ dinv,
                                                   const float* __restrict__ skip,
                                                   const float* __restrict__ bias,
                                                   float* __restrict__ OUT, int n) {
  const int lane = threadIdx.x & 15;
  const int node = blockIdx.x * 16 + (threadIdx.x >> 4);
  if (node >= n) return;

  const float dv = dinv[node];
  float acc[8];
  {
    uint4 sv = Hq[(size_t)node * 16 + lane];  // self term: tb_s[node]
    unpack8(sv, acc);
  }
  gather_row(acc, Hq, csr, rowse[node], lane);

  const float* sp = skip + (size_t)node * 128 + lane * 8;
  const float* bp = bias + lane * 8;
  float4 s0 = *(const float4*)sp, s1 = *(const float4*)(sp + 4);
  float4 b0 = *(const float4*)bp, b1 = *(const float4*)(bp + 4);
  float* op = OUT + (size_t)node * 128 + lane * 8;
  *(float4*)op = make_float4(fmaf(acc[0], dv, s0.x + b0.x), fmaf(acc[1], dv, s0.y + b0.y),
                             fmaf(acc[2], dv, s0.z + b0.z), fmaf(acc[3], dv, s0.w + b0.w));
  *(float4*)(op + 4) = make_float4(fmaf(acc[4], dv, s1.x + b1.x), fmaf(acc[5], dv, s1.y + b1.y),
                                   fmaf(acc[6], dv, s1.z + b1.z), fmaf(acc[7], dv, s1.w + b1.w));
}

// ================= launch =================

extern "C" void kernel_launch(void* const* d_in, const int* in_sizes, int n_in,
                              void* d_out, int out_size, void* d_ws, size_t ws_size,
                              hipStream_t stream) {
  const float* x  = (const float*)d_in[0];
  const int*   ei = (const int*)d_in[1];
  const float* W1 = (const float*)d_in[2];
  const float* b1 = (const float*)d_in[3];
  const float* W2 = (const float*)d_in[4];
  const float* b2 = (const float*)d_in[5];
  float* out = (float*)d_out;

  const int N = in_sizes[0] / D_IN;      // requires N <= 65536 (packed ebuf)
  const int E = in_sizes[1] / 2;
  const int* srcA = ei;
  const int* dstA = ei + E;
  const int NBKT = (N + BKT_SIZE - 1) >> BKT_SHIFT;  // 782 for N=50000
  const int NCHUNK = (E + CHUNK - 1) / CHUNK;        // 391

  // ---- workspace (256B aligned) ----
  char* ws = (char*)d_ws;
  size_t off = 0;
  auto alloc = [&](size_t bytes) { void* p = ws + off; off = (off + bytes + 255) & ~(size_t)255; return p; };
  int*            bkt_cursor = (int*)           alloc((size_t)NBKT * 4);
  float*          dinv       = (float*)         alloc((size_t)(N + 1) * 4);  // +sentinel
  int2*           rowse      = (int2*)          alloc((size_t)N * 8);
  int*            ebuf       = (int*)           alloc((size_t)NBKT * BKT_CAP * 4);
  int*            csr        = (int*)           alloc((size_t)NBKT * (BKT_CAP + PAD_SLACK) * 4);
  unsigned short* xb         = (unsigned short*)alloc((size_t)(N + 1) * D_IN * 2);
  unsigned short* tb         = (unsigned short*)alloc((size_t)(N + 1) * D_IN * 2);
  unsigned short* Wt1        = (unsigned short*)alloc((size_t)D_IN * HID * 2);
  unsigned short* Wt2        = (unsigned short*)alloc((size_t)D_IN * HID * 2);

  // 1) zero relative bucket cursors
  (void)hipMemsetAsync(bkt_cursor, 0, (size_t)NBKT * 4, stream);
  // 2) K1: bin_scatter + W transposes + sentinels
  fused_front_kernel<<<NCHUNK + 256 + 1, 256, 0, stream>>>(
      srcA, dstA, bkt_cursor, ebuf, E, NBKT, NCHUNK,
      W1, Wt1, W2, Wt2, dinv, xb, tb, N);
  // 3) K2: per-bucket build + prescaled x->xb conversion (782 blocks)
  bucket_build_kernel<<<NBKT, 256, 0, stream>>>(ebuf, bkt_cursor, (const float4*)x,
                                                xb, dinv, rowse, csr, N, NBKT);
  // 4) K3: tb_s = dinv * (relu((Â x) @ W1 + b1) @ W2)
  agg1_gemm_kernel<<<(N + 31) / 32, 512, 0, stream>>>((const uint4*)xb, rowse, csr, dinv,
                                                      Wt1, b1, Wt2, tb, N);
  // 5) K4: out = Â tb + x + b2   (gather of prescaled tb_s, final *dv)
  agg2_kernel<<<(N + 15) / 16, 256, 0, stream>>>((const uint4*)tb, rowse, csr,
                                                 dinv, x, b2, out, N);
}